// Round 1
// baseline (9967.619 us; speedup 1.0000x reference)
//
#include <hip/hip_runtime.h>
#include <stdint.h>
#include <stddef.h>

#define B_  64
#define S_  512
#define I_  512
#define H_  1024
#define G_  3072
#define BS_ 32768
#define NWG 96

typedef short short8 __attribute__((ext_vector_type(8)));
typedef float f32x4  __attribute__((ext_vector_type(4)));
typedef unsigned short u16x4 __attribute__((ext_vector_type(4)));

__device__ __forceinline__ unsigned short f32_to_bf16(float f){
  unsigned u = __builtin_bit_cast(unsigned, f);
  u = (u + 0x7FFFu + ((u >> 16) & 1u)) >> 16;
  return (unsigned short)u;
}
__device__ __forceinline__ float bf16_to_f32(unsigned short s){
  unsigned u = ((unsigned)s) << 16;
  return __builtin_bit_cast(float, u);
}
__device__ __forceinline__ float sig_(float x){ return 1.0f/(1.0f + __expf(-x)); }
__device__ __forceinline__ float tanh_(float x){
  float ax = fabsf(x);
  float t = __expf(-2.0f*ax);
  float r = (1.0f - t)/(1.0f + t);
  return copysignf(r, x);
}

// ---------------- f32 -> bf16 cast (vectorized, grid-stride) ----------------
__global__ __launch_bounds__(256) void k_cvt4(const float* __restrict__ src,
                                              unsigned short* __restrict__ dst, int n4){
  int i = blockIdx.x*blockDim.x + threadIdx.x;
  int st = gridDim.x*blockDim.x;
  for (; i < n4; i += st){
    f32x4 v = *(const f32x4*)(src + (size_t)i*4);
    u16x4 o;
    o[0]=f32_to_bf16(v[0]); o[1]=f32_to_bf16(v[1]);
    o[2]=f32_to_bf16(v[2]); o[3]=f32_to_bf16(v[3]);
    *(u16x4*)(dst + (size_t)i*4) = o;
  }
}

// ---------------- ih = X @ Wih^T   (bf16 MFMA, 128x128 tile) ----------------
__global__ __launch_bounds__(256, 2) void k_gemm_ih(
    const unsigned short* __restrict__ X,    // [32768][512]
    const unsigned short* __restrict__ W,    // [3072][512]
    unsigned short* __restrict__ IH)         // [32768][3072]
{
  __shared__ __align__(16) short As[128*32];
  __shared__ __align__(16) short Bs[128*32];
  int bid = blockIdx.x;
  int mt = bid / 24, nt = bid % 24;
  int tid = threadIdx.x, lane = tid & 63, wid = tid >> 6;
  int vr = wid >> 1, vc = wid & 1;
  int r0s = tid >> 2, r1s = r0s + 64;
  int sc = (tid & 3) * 8;
  const unsigned short* xa0 = X + (size_t)(mt*128 + r0s)*512 + sc;
  const unsigned short* xa1 = X + (size_t)(mt*128 + r1s)*512 + sc;
  const unsigned short* wb0 = W + (size_t)(nt*128 + r0s)*512 + sc;
  const unsigned short* wb1 = W + (size_t)(nt*128 + r1s)*512 + sc;

  f32x4 acc[4][4];
  #pragma unroll
  for (int m=0;m<4;m++)
    #pragma unroll
    for (int n=0;n<4;n++) acc[m][n] = (f32x4){0.f,0.f,0.f,0.f};

  short8 ra0 = *(const short8*)xa0;
  short8 ra1 = *(const short8*)xa1;
  short8 rb0 = *(const short8*)wb0;
  short8 rb1 = *(const short8*)wb1;
  int ko = (lane >> 4) * 8;

  for (int kt = 0; kt < 16; ++kt){
    __syncthreads();
    *(short8*)&As[r0s*32 + sc] = ra0;
    *(short8*)&As[r1s*32 + sc] = ra1;
    *(short8*)&Bs[r0s*32 + sc] = rb0;
    *(short8*)&Bs[r1s*32 + sc] = rb1;
    __syncthreads();
    if (kt < 15){
      ra0 = *(const short8*)(xa0 + (kt+1)*32);
      ra1 = *(const short8*)(xa1 + (kt+1)*32);
      rb0 = *(const short8*)(wb0 + (kt+1)*32);
      rb1 = *(const short8*)(wb1 + (kt+1)*32);
    }
    short8 af[4], bfr[4];
    #pragma unroll
    for (int m=0;m<4;m++) af[m]  = *(const short8*)&As[(vr*64 + m*16 + (lane&15))*32 + ko];
    #pragma unroll
    for (int n=0;n<4;n++) bfr[n] = *(const short8*)&Bs[(vc*64 + n*16 + (lane&15))*32 + ko];
    #pragma unroll
    for (int m=0;m<4;m++)
      #pragma unroll
      for (int n=0;n<4;n++)
        acc[m][n] = __builtin_amdgcn_mfma_f32_16x16x32_bf16(af[m], bfr[n], acc[m][n], 0,0,0);
  }
  int row0 = mt*128 + vr*64, col0 = nt*128 + vc*64;
  int rl = (lane >> 4) * 4, cl = lane & 15;
  #pragma unroll
  for (int m=0;m<4;m++)
    #pragma unroll
    for (int n=0;n<4;n++)
      #pragma unroll
      for (int r=0;r<4;r++)
        IH[(size_t)(row0 + m*16 + rl + r)*G_ + (col0 + n*16 + cl)] = f32_to_bf16(acc[m][n][r]);
}

// ---------------- row LayerNorm (ddof=1) over [0:2048) and [2048:3072) ------
__global__ __launch_bounds__(256) void k_ln(
    unsigned short* __restrict__ IH,
    const float* __restrict__ gih,
    const float* __restrict__ bih)
{
  __shared__ float red[4][4];
  int row = blockIdx.x, tid = threadIdx.x, lane = tid & 63, wid = tid >> 6;
  unsigned short* p = IH + (size_t)row * G_;
  float xv[3][4];
  #pragma unroll
  for (int q=0;q<3;q++){
    u16x4 v = *(const u16x4*)(p + (tid + q*256)*4);
    #pragma unroll
    for (int j=0;j<4;j++) xv[q][j] = bf16_to_f32(v[j]);
  }
  float s0=0, q0=0, s1=0, q1=0;
  #pragma unroll
  for (int q=0;q<2;q++)
    #pragma unroll
    for (int j=0;j<4;j++){ s0 += xv[q][j]; q0 += xv[q][j]*xv[q][j]; }
  #pragma unroll
  for (int j=0;j<4;j++){ s1 += xv[2][j]; q1 += xv[2][j]*xv[2][j]; }
  #pragma unroll
  for (int off=32; off>0; off>>=1){
    s0 += __shfl_down(s0, off, 64);
    q0 += __shfl_down(q0, off, 64);
    s1 += __shfl_down(s1, off, 64);
    q1 += __shfl_down(q1, off, 64);
  }
  if (lane == 0){ red[wid][0]=s0; red[wid][1]=q0; red[wid][2]=s1; red[wid][3]=q1; }
  __syncthreads();
  float S0 = red[0][0]+red[1][0]+red[2][0]+red[3][0];
  float Q0 = red[0][1]+red[1][1]+red[2][1]+red[3][1];
  float S1 = red[0][2]+red[1][2]+red[2][2]+red[3][2];
  float Q1 = red[0][3]+red[1][3]+red[2][3]+red[3][3];
  float m0 = S0 * (1.0f/2048.0f);
  float rs0 = rsqrtf(fmaxf((Q0 - S0*m0) * (1.0f/2047.0f), 1e-20f));
  float m1 = S1 * (1.0f/1024.0f);
  float rs1 = rsqrtf(fmaxf((Q1 - S1*m1) * (1.0f/1023.0f), 1e-20f));
  #pragma unroll
  for (int q=0;q<3;q++){
    int base = (tid + q*256)*4;
    u16x4 o;
    #pragma unroll
    for (int j=0;j<4;j++){
      int col = base + j;
      float y = (q<2) ? (xv[q][j]-m0)*rs0 : (xv[q][j]-m1)*rs1;
      o[j] = f32_to_bf16(gih[col]*y + bih[col]);
    }
    *(u16x4*)(p + base) = o;
  }
}

// ---------------- persistent GRU recurrence ---------------------------------
__device__ __forceinline__ void gbar(unsigned* bar, unsigned tgt){
  __syncthreads();
  if (threadIdx.x == 0){
    __hip_atomic_fetch_add(bar, 1u, __ATOMIC_RELEASE, __HIP_MEMORY_SCOPE_AGENT);
    while (__hip_atomic_load(bar, __ATOMIC_RELAXED, __HIP_MEMORY_SCOPE_AGENT) < tgt){
      __builtin_amdgcn_s_sleep(1);
    }
    __builtin_amdgcn_fence(__ATOMIC_ACQUIRE, "agent");
  }
  __syncthreads();
}

__global__ __launch_bounds__(256, 1) void k_gru(
    const unsigned short* __restrict__ IH,    // [64][512][3072] bf16 (post-LN)
    const unsigned short* __restrict__ WHH,   // [3072][1024] bf16
    unsigned short* __restrict__ HB,          // [64][1024] bf16 (current h)
    float* __restrict__ HHB,                  // [64][3072] f32 scratch
    const float* __restrict__ ghh,
    const float* __restrict__ bhh,
    const float* __restrict__ state,
    float* __restrict__ out,                  // [64][512][1024] f32 + final [64][1024]
    unsigned* __restrict__ bar)
{
  __shared__ float red[4][2];
  int w = blockIdx.x, tid = threadIdx.x, lane = tid & 63, wid = tid >> 6;
  int l15 = lane & 15, lho = (lane >> 4) << 3;

  // persistent W_hh strip in VGPRs: cols [w*32, w*32+32), full K=1024
  short8 bw0[32], bw1[32];
  #pragma unroll
  for (int kk=0;kk<32;kk++){
    int g0 = w*32 + l15;
    bw0[kk] = *(const short8*)(WHH + (size_t)g0*H_      + kk*32 + lho);
    bw1[kk] = *(const short8*)(WHH + (size_t)(g0+16)*H_ + kk*32 + lho);
  }

  float hreg[4], gr[4],gz[4],gn[4],brr[4],bzz[4],bnn[4];
  int j0 = tid*4;
  if (w < B_){
    #pragma unroll
    for (int j=0;j<4;j++){
      hreg[j] = state[w*H_ + j0 + j];
      gr[j] = ghh[j0+j];       gz[j] = ghh[H_+j0+j];  gn[j] = ghh[2*H_+j0+j];
      brr[j]= bhh[j0+j];       bzz[j]= bhh[H_+j0+j];  bnn[j]= bhh[2*H_+j0+j];
    }
  }

  int arow = wid*16 + l15;                 // batch row for A-frag
  int crow = wid*16 + (lane>>4)*4;         // C row base
  int ccol = w*32 + l15;                   // C col base
  unsigned tgt = NWG;

  for (int t=0; t<S_; ++t){
    // phase 1: hh strip = h @ Whh^T
    f32x4 a0 = {0.f,0.f,0.f,0.f}, a1 = {0.f,0.f,0.f,0.f};
    #pragma unroll
    for (int kk=0;kk<32;kk++){
      short8 a = *(const short8*)(HB + arow*H_ + kk*32 + lho);
      a0 = __builtin_amdgcn_mfma_f32_16x16x32_bf16(a, bw0[kk], a0, 0,0,0);
      a1 = __builtin_amdgcn_mfma_f32_16x16x32_bf16(a, bw1[kk], a1, 0,0,0);
    }
    #pragma unroll
    for (int r=0;r<4;r++){
      HHB[(crow+r)*G_ + ccol]      = a0[r];
      HHB[(crow+r)*G_ + ccol + 16] = a1[r];
    }
    gbar(bar, tgt); tgt += NWG;

    // phase 2: gates + h update (wg w handles batch b=w)
    if (w < B_){
      const f32x4* hrow = (const f32x4*)(HHB + (size_t)w*G_);
      f32x4 v0 = hrow[tid], v1 = hrow[tid+256], v2 = hrow[tid+512];
      float srz = v0[0]+v0[1]+v0[2]+v0[3] + v1[0]+v1[1]+v1[2]+v1[3];
      float sn  = v2[0]+v2[1]+v2[2]+v2[3];
      #pragma unroll
      for (int off=32; off>0; off>>=1){
        srz += __shfl_down(srz, off, 64);
        sn  += __shfl_down(sn,  off, 64);
      }
      if (lane==0){ red[wid][0]=srz; red[wid][1]=sn; }
      __syncthreads();
      float mrz = (red[0][0]+red[1][0]+red[2][0]+red[3][0]) * (1.0f/2048.0f);
      float mn  = (red[0][1]+red[1][1]+red[2][1]+red[3][1]) * (1.0f/1024.0f);
      const unsigned short* ihp = IH + ((size_t)w*S_ + t)*G_;
      u16x4 ir  = *(const u16x4*)(ihp + j0);
      u16x4 izv = *(const u16x4*)(ihp + H_ + j0);
      u16x4 inv = *(const u16x4*)(ihp + 2*H_ + j0);
      #pragma unroll
      for (int j=0;j<4;j++){
        float hr = gr[j]*(v0[j]-mrz) + brr[j];
        float hz = gz[j]*(v1[j]-mrz) + bzz[j];
        float hn = gn[j]*(v2[j]-mn ) + bnn[j];
        float rr = sig_(bf16_to_f32(ir[j])  + hr);
        float zz = sig_(bf16_to_f32(izv[j]) + hz);
        float nn = tanh_(bf16_to_f32(inv[j]) + rr*hn);
        hreg[j] = (1.0f-zz)*nn + zz*hreg[j];
      }
      f32x4 ho = {hreg[0],hreg[1],hreg[2],hreg[3]};
      *(f32x4*)(out + ((size_t)w*S_ + t)*H_ + j0) = ho;
      u16x4 hb;
      #pragma unroll
      for (int j=0;j<4;j++) hb[j] = f32_to_bf16(hreg[j]);
      *(u16x4*)(HB + w*H_ + j0) = hb;
    }
    gbar(bar, tgt); tgt += NWG;
  }
  if (w < B_){
    #pragma unroll
    for (int j=0;j<4;j++) out[(size_t)B_*S_*H_ + w*H_ + j0 + j] = hreg[j];
  }
}

// ---------------- host launcher ---------------------------------------------
extern "C" void kernel_launch(void* const* d_in, const int* in_sizes, int n_in,
                              void* d_out, int out_size, void* d_ws, size_t ws_size,
                              hipStream_t stream){
  (void)in_sizes; (void)n_in; (void)out_size; (void)ws_size;
  const float* x   = (const float*)d_in[0];
  const float* st  = (const float*)d_in[1];
  const float* wih = (const float*)d_in[2];
  const float* whh = (const float*)d_in[3];
  const float* bih = (const float*)d_in[4];
  const float* bhh = (const float*)d_in[5];
  const float* gih = (const float*)d_in[6];
  const float* ghh = (const float*)d_in[7];
  float* out = (float*)d_out;
  char* ws = (char*)d_ws;

  // ws layout (245,235,840 bytes total)
  unsigned short* IH    = (unsigned short*)(ws);                   // 201,326,592
  unsigned short* X16   = (unsigned short*)(ws + 201326592ull);    //  33,554,432
  unsigned short* WIH16 = (unsigned short*)(ws + 234881024ull);    //   3,145,728
  unsigned short* WHH16 = (unsigned short*)(ws + 238026752ull);    //   6,291,456
  unsigned short* HB    = (unsigned short*)(ws + 244318208ull);    //     131,072
  float*          HHB   = (float*)         (ws + 244449280ull);    //     786,432
  unsigned*       BAR   = (unsigned*)      (ws + 245235712ull);    //         128

  hipMemsetAsync(BAR, 0, 128, stream);
  k_cvt4<<<2048, 256, 0, stream>>>(x,   X16,   16777216/4);
  k_cvt4<<<1024, 256, 0, stream>>>(wih, WIH16, 1572864/4);
  k_cvt4<<<1024, 256, 0, stream>>>(whh, WHH16, 3145728/4);
  k_cvt4<<<64,   256, 0, stream>>>(st,  HB,    65536/4);
  k_gemm_ih<<<6144, 256, 0, stream>>>(X16, WIH16, IH);
  k_ln<<<32768, 256, 0, stream>>>(IH, gih, bih);
  k_gru<<<NWG, 256, 0, stream>>>(IH, WHH16, HB, HHB, ghh, bhh, st, out, BAR);
}

// Round 2
// 5820.982 us; speedup vs baseline: 1.7124x; 1.7124x over previous
//
#include <hip/hip_runtime.h>
#include <stdint.h>
#include <stddef.h>

#define B_  64
#define S_  512
#define I_  512
#define H_  1024
#define G_  3072
#define NWG 64
#define CPW 16

typedef short short8 __attribute__((ext_vector_type(8)));
typedef float f32x4  __attribute__((ext_vector_type(4)));
typedef unsigned short u16x4 __attribute__((ext_vector_type(4)));

__device__ __forceinline__ unsigned short f32_to_bf16(float f){
  unsigned u = __builtin_bit_cast(unsigned, f);
  u = (u + 0x7FFFu + ((u >> 16) & 1u)) >> 16;
  return (unsigned short)u;
}
__device__ __forceinline__ float bf16_to_f32(unsigned short s){
  unsigned u = ((unsigned)s) << 16;
  return __builtin_bit_cast(float, u);
}
__device__ __forceinline__ float sig_(float x){ return 1.0f/(1.0f + __expf(-x)); }
__device__ __forceinline__ float tanh_(float x){
  float ax = fabsf(x);
  float t = __expf(-2.0f*ax);
  float r = (1.0f - t)/(1.0f + t);
  return copysignf(r, x);
}

// coherent (cross-XCD visible) 16B load / 8B store: bypass L1/L2 via sc0 sc1
__device__ __forceinline__ short8 ldg16_coh(const unsigned short* p){
  short8 r;
  asm volatile("global_load_dwordx4 %0, %1, off sc0 sc1" : "=v"(r) : "v"(p) : "memory");
  return r;
}
__device__ __forceinline__ void stg8_coh(unsigned short* p, u16x4 v){
  asm volatile("global_store_dwordx2 %0, %1, off sc0 sc1" :: "v"(p), "v"(v) : "memory");
}

// ---------------- f32 -> bf16 cast ----------------
__global__ __launch_bounds__(256) void k_cvt4(const float* __restrict__ src,
                                              unsigned short* __restrict__ dst, int n4){
  int i = blockIdx.x*blockDim.x + threadIdx.x;
  int st = gridDim.x*blockDim.x;
  for (; i < n4; i += st){
    f32x4 v = *(const f32x4*)(src + (size_t)i*4);
    u16x4 o;
    o[0]=f32_to_bf16(v[0]); o[1]=f32_to_bf16(v[1]);
    o[2]=f32_to_bf16(v[2]); o[3]=f32_to_bf16(v[3]);
    *(u16x4*)(dst + (size_t)i*4) = o;
  }
}

// ---------------- column means of Whh (rz block and n block) -> CM[16][1024]
__global__ __launch_bounds__(256) void k_cmean(const float* __restrict__ whh,
                                               unsigned short* __restrict__ CM){
  int k = blockIdx.x*256 + threadIdx.x;   // grid = 4 x 256 -> k in [0,1024)
  float s0 = 0.f, s1 = 0.f;
  for (int j = 0; j < 2048; ++j) s0 += whh[(size_t)j*H_ + k];
  for (int j = 2048; j < 3072; ++j) s1 += whh[(size_t)j*H_ + k];
  CM[k]      = f32_to_bf16(s0 * (1.0f/2048.0f));
  CM[H_ + k] = f32_to_bf16(s1 * (1.0f/1024.0f));
  for (int r = 2; r < 16; ++r) CM[(size_t)r*H_ + k] = 0;
}

// ---------------- ih = X @ Wih^T  (writes time-major: row' = s*64 + b) ------
__global__ __launch_bounds__(256, 2) void k_gemm_ih(
    const unsigned short* __restrict__ X,    // [32768][512]
    const unsigned short* __restrict__ W,    // [3072][512]
    unsigned short* __restrict__ IH)         // [512][64][3072]
{
  __shared__ __align__(16) short As[128*32];
  __shared__ __align__(16) short Bs[128*32];
  int bid = blockIdx.x;
  int mt = bid / 24, nt = bid % 24;
  int tid = threadIdx.x, lane = tid & 63, wid = tid >> 6;
  int vr = wid >> 1, vc = wid & 1;
  int r0s = tid >> 2, r1s = r0s + 64;
  int sc = (tid & 3) * 8;
  const unsigned short* xa0 = X + (size_t)(mt*128 + r0s)*512 + sc;
  const unsigned short* xa1 = X + (size_t)(mt*128 + r1s)*512 + sc;
  const unsigned short* wb0 = W + (size_t)(nt*128 + r0s)*512 + sc;
  const unsigned short* wb1 = W + (size_t)(nt*128 + r1s)*512 + sc;

  f32x4 acc[4][4];
  #pragma unroll
  for (int m=0;m<4;m++)
    #pragma unroll
    for (int n=0;n<4;n++) acc[m][n] = (f32x4){0.f,0.f,0.f,0.f};

  short8 ra0 = *(const short8*)xa0;
  short8 ra1 = *(const short8*)xa1;
  short8 rb0 = *(const short8*)wb0;
  short8 rb1 = *(const short8*)wb1;
  int ko = (lane >> 4) * 8;

  for (int kt = 0; kt < 16; ++kt){
    __syncthreads();
    *(short8*)&As[r0s*32 + sc] = ra0;
    *(short8*)&As[r1s*32 + sc] = ra1;
    *(short8*)&Bs[r0s*32 + sc] = rb0;
    *(short8*)&Bs[r1s*32 + sc] = rb1;
    __syncthreads();
    if (kt < 15){
      ra0 = *(const short8*)(xa0 + (kt+1)*32);
      ra1 = *(const short8*)(xa1 + (kt+1)*32);
      rb0 = *(const short8*)(wb0 + (kt+1)*32);
      rb1 = *(const short8*)(wb1 + (kt+1)*32);
    }
    short8 af[4], bfr[4];
    #pragma unroll
    for (int m=0;m<4;m++) af[m]  = *(const short8*)&As[(vr*64 + m*16 + (lane&15))*32 + ko];
    #pragma unroll
    for (int n=0;n<4;n++) bfr[n] = *(const short8*)&Bs[(vc*64 + n*16 + (lane&15))*32 + ko];
    #pragma unroll
    for (int m=0;m<4;m++)
      #pragma unroll
      for (int n=0;n<4;n++)
        acc[m][n] = __builtin_amdgcn_mfma_f32_16x16x32_bf16(af[m], bfr[n], acc[m][n], 0,0,0);
  }
  int row0 = mt*128 + vr*64, col0 = nt*128 + vc*64;
  int rl = (lane >> 4) * 4, cl = lane & 15;
  #pragma unroll
  for (int m=0;m<4;m++)
    #pragma unroll
    for (int n=0;n<4;n++)
      #pragma unroll
      for (int r=0;r<4;r++){
        int row = row0 + m*16 + rl + r;             // b*512 + s
        int rowT = ((row & 511) << 6) | (row >> 9); // s*64 + b
        IH[(size_t)rowT*G_ + (col0 + n*16 + cl)] = f32_to_bf16(acc[m][n][r]);
      }
}

// ---------------- row LayerNorm (ddof=1) over [0:2048) and [2048:3072) ------
__global__ __launch_bounds__(256) void k_ln(
    unsigned short* __restrict__ IH,
    const float* __restrict__ gih,
    const float* __restrict__ bih)
{
  __shared__ float red[4][4];
  int row = blockIdx.x, tid = threadIdx.x, lane = tid & 63, wid = tid >> 6;
  unsigned short* p = IH + (size_t)row * G_;
  float xv[3][4];
  #pragma unroll
  for (int q=0;q<3;q++){
    u16x4 v = *(const u16x4*)(p + (tid + q*256)*4);
    #pragma unroll
    for (int j=0;j<4;j++) xv[q][j] = bf16_to_f32(v[j]);
  }
  float s0=0, q0=0, s1=0, q1=0;
  #pragma unroll
  for (int q=0;q<2;q++)
    #pragma unroll
    for (int j=0;j<4;j++){ s0 += xv[q][j]; q0 += xv[q][j]*xv[q][j]; }
  #pragma unroll
  for (int j=0;j<4;j++){ s1 += xv[2][j]; q1 += xv[2][j]*xv[2][j]; }
  #pragma unroll
  for (int off=32; off>0; off>>=1){
    s0 += __shfl_down(s0, off, 64);
    q0 += __shfl_down(q0, off, 64);
    s1 += __shfl_down(s1, off, 64);
    q1 += __shfl_down(q1, off, 64);
  }
  if (lane == 0){ red[wid][0]=s0; red[wid][1]=q0; red[wid][2]=s1; red[wid][3]=q1; }
  __syncthreads();
  float S0 = red[0][0]+red[1][0]+red[2][0]+red[3][0];
  float Q0 = red[0][1]+red[1][1]+red[2][1]+red[3][1];
  float S1 = red[0][2]+red[1][2]+red[2][2]+red[3][2];
  float Q1 = red[0][3]+red[1][3]+red[2][3]+red[3][3];
  float m0 = S0 * (1.0f/2048.0f);
  float rs0 = rsqrtf(fmaxf((Q0 - S0*m0) * (1.0f/2047.0f), 1e-20f));
  float m1 = S1 * (1.0f/1024.0f);
  float rs1 = rsqrtf(fmaxf((Q1 - S1*m1) * (1.0f/1023.0f), 1e-20f));
  #pragma unroll
  for (int q=0;q<3;q++){
    int base = (tid + q*256)*4;
    u16x4 o;
    #pragma unroll
    for (int j=0;j<4;j++){
      int col = base + j;
      float y = (q<2) ? (xv[q][j]-m0)*rs0 : (xv[q][j]-m1)*rs1;
      o[j] = f32_to_bf16(gih[col]*y + bih[col]);
    }
    *(u16x4*)(p + base) = o;
  }
}

// ---------------- persistent GRU recurrence (1 barrier/step, fence-free) ----
__global__ __launch_bounds__(256, 1) void k_gru(
    const unsigned short* __restrict__ IH,   // [512][64][3072] bf16 post-LN
    const unsigned short* __restrict__ WHH,  // [3072][1024] bf16
    const unsigned short* __restrict__ CM,   // [16][1024] bf16 (rows 0,1 = c_rz, c_n)
    unsigned short* __restrict__ HB,         // 2 x [64][1024] bf16 ping-pong
    const float* __restrict__ ghh,
    const float* __restrict__ bhh,
    const float* __restrict__ state,
    float* __restrict__ out,
    unsigned* __restrict__ bar)
{
  __shared__ float PSUM[4][64][68];
  const int g = blockIdx.x;
  const int tid = threadIdx.x;
  const int lane = tid & 63;
  const int wv = tid >> 6;              // wave = K-quarter owner
  const int l15 = lane & 15;
  const int lho = (lane >> 4) << 3;
  const int colbase = g * CPW;

  // persistent B fragments: 3 gate col-tiles + 1 mean tile, K-quarter of this wave
  short8 bfr[4][8];
  #pragma unroll
  for (int ct = 0; ct < 4; ++ct){
    const unsigned short* src = (ct < 3)
        ? (WHH + (size_t)(ct*H_ + colbase + l15)*H_)
        : (CM + (size_t)l15*H_);
    #pragma unroll
    for (int ks = 0; ks < 8; ++ks)
      bfr[ct][ks] = *(const short8*)(src + wv*256 + ks*32 + lho);
  }

  // gate-phase ownership: thread = (batch b, col-quad cq)
  const int b = tid & 63;
  const int cq = tid >> 6;
  const int c0 = colbase + cq*4;
  float gr[4],gz[4],gn[4],br_[4],bz_[4],bn_[4],hv[4];
  #pragma unroll
  for (int j = 0; j < 4; ++j){
    gr[j] = ghh[c0+j];   gz[j] = ghh[H_+c0+j];   gn[j] = ghh[2*H_+c0+j];
    br_[j]= bhh[c0+j];   bz_[j]= bhh[H_+c0+j];   bn_[j]= bhh[2*H_+c0+j];
    hv[j] = state[(size_t)b*H_ + c0 + j];
  }

  unsigned tgt = NWG;
  int cur = 0;

  for (int t = 0; t < S_; ++t){
    // ih gate inputs (read-only, cached) — issue early
    const unsigned short* ihp = IH + ((size_t)t*B_ + b)*G_;
    u16x4 ir  = *(const u16x4*)(ihp + c0);
    u16x4 izv = *(const u16x4*)(ihp + H_ + c0);
    u16x4 inv = *(const u16x4*)(ihp + 2*H_ + c0);

    // A fragments: coherent read of h panel (each wave its K-quarter)
    const unsigned short* hb = HB + cur*(B_*H_);
    short8 af[4][8];
    #pragma unroll
    for (int rt = 0; rt < 4; ++rt)
      #pragma unroll
      for (int ks = 0; ks < 8; ++ks)
        af[rt][ks] = ldg16_coh(hb + (size_t)(rt*16 + l15)*H_ + wv*256 + ks*32 + lho);
    asm volatile("s_waitcnt vmcnt(0)" ::: "memory");
    __builtin_amdgcn_sched_barrier(0);

    f32x4 acc[4][4];
    #pragma unroll
    for (int ct = 0; ct < 4; ++ct)
      #pragma unroll
      for (int rt = 0; rt < 4; ++rt)
        acc[ct][rt] = (f32x4){0.f,0.f,0.f,0.f};
    #pragma unroll
    for (int ks = 0; ks < 8; ++ks)
      #pragma unroll
      for (int rt = 0; rt < 4; ++rt)
        #pragma unroll
        for (int ct = 0; ct < 4; ++ct)
          acc[ct][rt] = __builtin_amdgcn_mfma_f32_16x16x32_bf16(af[rt][ks], bfr[ct][ks], acc[ct][rt], 0,0,0);

    // K-partials -> LDS (prev step's reads were fenced by the global barrier)
    #pragma unroll
    for (int ct = 0; ct < 4; ++ct)
      #pragma unroll
      for (int rt = 0; rt < 4; ++rt)
        *(f32x4*)&PSUM[wv][ct*16 + l15][rt*16 + (lane>>4)*4] = acc[ct][rt];
    __syncthreads();

    // reduce 4 K-quarters, compute gates and h update
    float hhr[4]={0,0,0,0}, hhz[4]={0,0,0,0}, hhn[4]={0,0,0,0};
    float mrz = 0.f, mn = 0.f;
    #pragma unroll
    for (int w = 0; w < 4; ++w){
      #pragma unroll
      for (int j = 0; j < 4; ++j){
        hhr[j] += PSUM[w][cq*4 + j][b];
        hhz[j] += PSUM[w][16 + cq*4 + j][b];
        hhn[j] += PSUM[w][32 + cq*4 + j][b];
      }
      mrz += PSUM[w][48][b];
      mn  += PSUM[w][49][b];
    }
    #pragma unroll
    for (int j = 0; j < 4; ++j){
      float R = sig_(bf16_to_f32(ir[j])  + gr[j]*(hhr[j]-mrz) + br_[j]);
      float Z = sig_(bf16_to_f32(izv[j]) + gz[j]*(hhz[j]-mrz) + bz_[j]);
      float N = tanh_(bf16_to_f32(inv[j]) + R*(gn[j]*(hhn[j]-mn) + bn_[j]));
      hv[j] = (1.0f - Z)*N + Z*hv[j];
    }
    *(f32x4*)(out + ((size_t)b*S_ + t)*H_ + c0) = (f32x4){hv[0],hv[1],hv[2],hv[3]};
    u16x4 h16;
    #pragma unroll
    for (int j = 0; j < 4; ++j) h16[j] = f32_to_bf16(hv[j]);
    stg8_coh(HB + (cur^1)*(B_*H_) + (size_t)b*H_ + c0, h16);

    // fence-free epoch barrier
    asm volatile("s_waitcnt vmcnt(0)" ::: "memory");
    __syncthreads();
    if (tid == 0){
      __hip_atomic_fetch_add(bar, 1u, __ATOMIC_RELAXED, __HIP_MEMORY_SCOPE_AGENT);
      while (__hip_atomic_load(bar, __ATOMIC_RELAXED, __HIP_MEMORY_SCOPE_AGENT) < tgt)
        __builtin_amdgcn_s_sleep(1);
    }
    __syncthreads();
    tgt += NWG;
    cur ^= 1;
  }
  #pragma unroll
  for (int j = 0; j < 4; ++j)
    out[(size_t)B_*S_*H_ + (size_t)b*H_ + c0 + j] = hv[j];
}

// ---------------- host launcher ---------------------------------------------
extern "C" void kernel_launch(void* const* d_in, const int* in_sizes, int n_in,
                              void* d_out, int out_size, void* d_ws, size_t ws_size,
                              hipStream_t stream){
  (void)in_sizes; (void)n_in; (void)out_size; (void)ws_size;
  const float* x   = (const float*)d_in[0];
  const float* st  = (const float*)d_in[1];
  const float* wih = (const float*)d_in[2];
  const float* whh = (const float*)d_in[3];
  const float* bih = (const float*)d_in[4];
  const float* bhh = (const float*)d_in[5];
  const float* gih = (const float*)d_in[6];
  const float* ghh = (const float*)d_in[7];
  float* out = (float*)d_out;
  char* ws = (char*)d_ws;

  unsigned short* IH    = (unsigned short*)(ws);                   // 201,326,592
  unsigned short* X16   = (unsigned short*)(ws + 201326592ull);    //  33,554,432
  unsigned short* WIH16 = (unsigned short*)(ws + 234881024ull);    //   3,145,728
  unsigned short* WHH16 = (unsigned short*)(ws + 238026752ull);    //   6,291,456
  unsigned short* CM16  = (unsigned short*)(ws + 244318208ull);    //      32,768
  unsigned short* HB    = (unsigned short*)(ws + 244350976ull);    //     262,144
  unsigned*       BAR   = (unsigned*)      (ws + 244613120ull);    //         128

  hipMemsetAsync(BAR, 0, 128, stream);
  k_cvt4<<<2048, 256, 0, stream>>>(x,   X16,   4194304);
  k_cvt4<<<1024, 256, 0, stream>>>(wih, WIH16, 393216);
  k_cvt4<<<1024, 256, 0, stream>>>(whh, WHH16, 786432);
  k_cvt4<<<64,   256, 0, stream>>>(st,  HB,    16384);
  k_cmean<<<4,   256, 0, stream>>>(whh, CM16);
  k_gemm_ih<<<6144, 256, 0, stream>>>(X16, WIH16, IH);
  k_ln<<<32768, 256, 0, stream>>>(IH, gih, bih);
  k_gru<<<NWG, 256, 0, stream>>>(IH, WHH16, CM16, HB, ghh, bhh, st, out, BAR);
}

// Round 3
// 4123.461 us; speedup vs baseline: 2.4173x; 1.4117x over previous
//
#include <hip/hip_runtime.h>
#include <stdint.h>
#include <stddef.h>

#define B_  64
#define S_  512
#define I_  512
#define H_  1024
#define G_  3072
#define NWG 64
#define CPW 16

typedef short short8 __attribute__((ext_vector_type(8)));
typedef float f32x4  __attribute__((ext_vector_type(4)));
typedef unsigned short u16x4 __attribute__((ext_vector_type(4)));

__device__ __forceinline__ unsigned short f32_to_bf16(float f){
  unsigned u = __builtin_bit_cast(unsigned, f);
  u = (u + 0x7FFFu + ((u >> 16) & 1u)) >> 16;
  return (unsigned short)u;
}
__device__ __forceinline__ float bf16_to_f32(unsigned short s){
  unsigned u = ((unsigned)s) << 16;
  return __builtin_bit_cast(float, u);
}
__device__ __forceinline__ float sig_(float x){ return 1.0f/(1.0f + __expf(-x)); }
__device__ __forceinline__ float tanh_(float x){
  float ax = fabsf(x);
  float t = __expf(-2.0f*ax);
  float r = (1.0f - t)/(1.0f + t);
  return copysignf(r, x);
}

// coherent (cross-XCD visible) accesses: bypass L1/L2 via sc0 sc1
__device__ __forceinline__ short8 ldg16_coh(const unsigned short* p){
  short8 r;
  asm volatile("global_load_dwordx4 %0, %1, off sc0 sc1" : "=v"(r) : "v"(p) : "memory");
  return r;
}
__device__ __forceinline__ void stg8_coh(unsigned short* p, u16x4 v){
  asm volatile("global_store_dwordx2 %0, %1, off sc0 sc1" :: "v"(p), "v"(v) : "memory");
}
__device__ __forceinline__ void stg4_coh(unsigned* p, unsigned v){
  asm volatile("global_store_dword %0, %1, off sc0 sc1" :: "v"(p), "v"(v) : "memory");
}
__device__ __forceinline__ unsigned ldg4_coh_wait(const unsigned* p){
  unsigned r;
  asm volatile("global_load_dword %0, %1, off sc0 sc1\n\ts_waitcnt vmcnt(0)"
               : "=v"(r) : "v"(p) : "memory");
  return r;
}
__device__ __forceinline__ u16x4 ldg8(const unsigned short* p){
  u16x4 r;
  asm volatile("global_load_dwordx2 %0, %1, off" : "=v"(r) : "v"(p) : "memory");
  return r;
}

// ---------------- f32 -> bf16 cast ----------------
__global__ __launch_bounds__(256) void k_cvt4(const float* __restrict__ src,
                                              unsigned short* __restrict__ dst, int n4){
  int i = blockIdx.x*blockDim.x + threadIdx.x;
  int st = gridDim.x*blockDim.x;
  for (; i < n4; i += st){
    f32x4 v = *(const f32x4*)(src + (size_t)i*4);
    u16x4 o;
    o[0]=f32_to_bf16(v[0]); o[1]=f32_to_bf16(v[1]);
    o[2]=f32_to_bf16(v[2]); o[3]=f32_to_bf16(v[3]);
    *(u16x4*)(dst + (size_t)i*4) = o;
  }
}

// ---------------- column means of Whh -> CM[16][1024] -----------------------
__global__ __launch_bounds__(256) void k_cmean(const float* __restrict__ whh,
                                               unsigned short* __restrict__ CM){
  int k = blockIdx.x*256 + threadIdx.x;   // grid = 4 x 256 -> k in [0,1024)
  float s0 = 0.f, s1 = 0.f;
  for (int j = 0; j < 2048; ++j) s0 += whh[(size_t)j*H_ + k];
  for (int j = 2048; j < 3072; ++j) s1 += whh[(size_t)j*H_ + k];
  CM[k]      = f32_to_bf16(s0 * (1.0f/2048.0f));
  CM[H_ + k] = f32_to_bf16(s1 * (1.0f/1024.0f));
  for (int r = 2; r < 16; ++r) CM[(size_t)r*H_ + k] = 0;
}

// ---------------- ih = X @ Wih^T  (writes time-major: row' = s*64 + b) ------
__global__ __launch_bounds__(256, 2) void k_gemm_ih(
    const unsigned short* __restrict__ X,    // [32768][512]
    const unsigned short* __restrict__ W,    // [3072][512]
    unsigned short* __restrict__ IH)         // [512][64][3072]
{
  __shared__ __align__(16) short As[128*32];
  __shared__ __align__(16) short Bs[128*32];
  int bid = blockIdx.x;
  int mt = bid / 24, nt = bid % 24;
  int tid = threadIdx.x, lane = tid & 63, wid = tid >> 6;
  int vr = wid >> 1, vc = wid & 1;
  int r0s = tid >> 2, r1s = r0s + 64;
  int sc = (tid & 3) * 8;
  const unsigned short* xa0 = X + (size_t)(mt*128 + r0s)*512 + sc;
  const unsigned short* xa1 = X + (size_t)(mt*128 + r1s)*512 + sc;
  const unsigned short* wb0 = W + (size_t)(nt*128 + r0s)*512 + sc;
  const unsigned short* wb1 = W + (size_t)(nt*128 + r1s)*512 + sc;

  f32x4 acc[4][4];
  #pragma unroll
  for (int m=0;m<4;m++)
    #pragma unroll
    for (int n=0;n<4;n++) acc[m][n] = (f32x4){0.f,0.f,0.f,0.f};

  short8 ra0 = *(const short8*)xa0;
  short8 ra1 = *(const short8*)xa1;
  short8 rb0 = *(const short8*)wb0;
  short8 rb1 = *(const short8*)wb1;
  int ko = (lane >> 4) * 8;

  for (int kt = 0; kt < 16; ++kt){
    __syncthreads();
    *(short8*)&As[r0s*32 + sc] = ra0;
    *(short8*)&As[r1s*32 + sc] = ra1;
    *(short8*)&Bs[r0s*32 + sc] = rb0;
    *(short8*)&Bs[r1s*32 + sc] = rb1;
    __syncthreads();
    if (kt < 15){
      ra0 = *(const short8*)(xa0 + (kt+1)*32);
      ra1 = *(const short8*)(xa1 + (kt+1)*32);
      rb0 = *(const short8*)(wb0 + (kt+1)*32);
      rb1 = *(const short8*)(wb1 + (kt+1)*32);
    }
    short8 af[4], bfr[4];
    #pragma unroll
    for (int m=0;m<4;m++) af[m]  = *(const short8*)&As[(vr*64 + m*16 + (lane&15))*32 + ko];
    #pragma unroll
    for (int n=0;n<4;n++) bfr[n] = *(const short8*)&Bs[(vc*64 + n*16 + (lane&15))*32 + ko];
    #pragma unroll
    for (int m=0;m<4;m++)
      #pragma unroll
      for (int n=0;n<4;n++)
        acc[m][n] = __builtin_amdgcn_mfma_f32_16x16x32_bf16(af[m], bfr[n], acc[m][n], 0,0,0);
  }
  int row0 = mt*128 + vr*64, col0 = nt*128 + vc*64;
  int rl = (lane >> 4) * 4, cl = lane & 15;
  #pragma unroll
  for (int m=0;m<4;m++)
    #pragma unroll
    for (int n=0;n<4;n++)
      #pragma unroll
      for (int r=0;r<4;r++){
        int row = row0 + m*16 + rl + r;             // b*512 + s
        int rowT = ((row & 511) << 6) | (row >> 9); // s*64 + b
        IH[(size_t)rowT*G_ + (col0 + n*16 + cl)] = f32_to_bf16(acc[m][n][r]);
      }
}

// ---------------- row LayerNorm (ddof=1) over [0:2048) and [2048:3072) ------
__global__ __launch_bounds__(256) void k_ln(
    unsigned short* __restrict__ IH,
    const float* __restrict__ gih,
    const float* __restrict__ bih)
{
  __shared__ float red[4][4];
  int row = blockIdx.x, tid = threadIdx.x, lane = tid & 63, wid = tid >> 6;
  unsigned short* p = IH + (size_t)row * G_;
  float xv[3][4];
  #pragma unroll
  for (int q=0;q<3;q++){
    u16x4 v = *(const u16x4*)(p + (tid + q*256)*4);
    #pragma unroll
    for (int j=0;j<4;j++) xv[q][j] = bf16_to_f32(v[j]);
  }
  float s0=0, q0=0, s1=0, q1=0;
  #pragma unroll
  for (int q=0;q<2;q++)
    #pragma unroll
    for (int j=0;j<4;j++){ s0 += xv[q][j]; q0 += xv[q][j]*xv[q][j]; }
  #pragma unroll
  for (int j=0;j<4;j++){ s1 += xv[2][j]; q1 += xv[2][j]*xv[2][j]; }
  #pragma unroll
  for (int off=32; off>0; off>>=1){
    s0 += __shfl_down(s0, off, 64);
    q0 += __shfl_down(q0, off, 64);
    s1 += __shfl_down(s1, off, 64);
    q1 += __shfl_down(q1, off, 64);
  }
  if (lane == 0){ red[wid][0]=s0; red[wid][1]=q0; red[wid][2]=s1; red[wid][3]=q1; }
  __syncthreads();
  float S0 = red[0][0]+red[1][0]+red[2][0]+red[3][0];
  float Q0 = red[0][1]+red[1][1]+red[2][1]+red[3][1];
  float S1 = red[0][2]+red[1][2]+red[2][2]+red[3][2];
  float Q1 = red[0][3]+red[1][3]+red[2][3]+red[3][3];
  float m0 = S0 * (1.0f/2048.0f);
  float rs0 = rsqrtf(fmaxf((Q0 - S0*m0) * (1.0f/2047.0f), 1e-20f));
  float m1 = S1 * (1.0f/1024.0f);
  float rs1 = rsqrtf(fmaxf((Q1 - S1*m1) * (1.0f/1023.0f), 1e-20f));
  #pragma unroll
  for (int q=0;q<3;q++){
    int base = (tid + q*256)*4;
    u16x4 o;
    #pragma unroll
    for (int j=0;j<4;j++){
      int col = base + j;
      float y = (q<2) ? (xv[q][j]-m0)*rs0 : (xv[q][j]-m1)*rs1;
      o[j] = f32_to_bf16(gih[col]*y + bih[col]);
    }
    *(u16x4*)(p + base) = o;
  }
}

// ---------------- persistent GRU recurrence (flag-array barrier) ------------
__global__ __launch_bounds__(256, 1) void k_gru(
    const unsigned short* __restrict__ IH,   // [512][64][3072] bf16 post-LN
    const unsigned short* __restrict__ WHH,  // [3072][1024] bf16
    const unsigned short* __restrict__ CM,   // [16][1024] bf16
    unsigned short* __restrict__ HB,         // 2 x [64][1024] bf16 ping-pong
    const float* __restrict__ ghh,
    const float* __restrict__ bhh,
    const float* __restrict__ state,
    float* __restrict__ out,
    unsigned* __restrict__ FLAGS)            // 64 flags, 64B apart
{
  __shared__ float PSUM[4][64][68];
  const int g = blockIdx.x;
  const int tid = threadIdx.x;
  const int lane = tid & 63;
  const int wv = tid >> 6;              // wave = K-quarter owner
  const int l15 = lane & 15;
  const int lho = (lane >> 4) << 3;
  const int colbase = g * CPW;

  // persistent B fragments: 3 gate col-tiles + 1 mean tile (K-quarter per wave)
  short8 bfr[4][8];
  #pragma unroll
  for (int ct = 0; ct < 4; ++ct){
    const unsigned short* src = (ct < 3)
        ? (WHH + (size_t)(ct*H_ + colbase + l15)*H_)
        : (CM + (size_t)l15*H_);
    #pragma unroll
    for (int ks = 0; ks < 8; ++ks)
      bfr[ct][ks] = *(const short8*)(src + wv*256 + ks*32 + lho);
  }

  // gate-phase ownership: thread = (batch b, col-quad cq)
  const int b = tid & 63;
  const int cq = tid >> 6;
  const int c0 = colbase + cq*4;
  float gr[4],gz[4],gn[4],br_[4],bz_[4],bn_[4],hv[4];
  #pragma unroll
  for (int j = 0; j < 4; ++j){
    gr[j] = ghh[c0+j];   gz[j] = ghh[H_+c0+j];   gn[j] = ghh[2*H_+c0+j];
    br_[j]= bhh[c0+j];   bz_[j]= bhh[H_+c0+j];   bn_[j]= bhh[2*H_+c0+j];
    hv[j] = state[(size_t)b*H_ + c0 + j];
  }

  const unsigned* myflag = FLAGS + lane*16;
  int cur = 0;

  for (int t = 0; t < S_; ++t){
    // ih gate inputs — issue before the poll so they ride under the wait
    const unsigned short* ihp = IH + ((size_t)t*B_ + b)*G_;
    u16x4 ir  = ldg8(ihp + c0);
    u16x4 izv = ldg8(ihp + H_ + c0);
    u16x4 inv = ldg8(ihp + 2*H_ + c0);

    // flag-array barrier: wait until every wg published h(t)
    // (lane i polls flag i; includes vmcnt(0) so IH loads are also drained)
    for (;;){
      unsigned v = ldg4_coh_wait(myflag);
      if (__all((int)(v >= (unsigned)t))) break;
    }

    // A fragments: coherent read of h panel, issued ks-major
    const unsigned short* hb = HB + cur*(B_*H_);
    short8 af[8][4];
    #pragma unroll
    for (int ks = 0; ks < 8; ++ks)
      #pragma unroll
      for (int rt = 0; rt < 4; ++rt)
        af[ks][rt] = ldg16_coh(hb + (size_t)(rt*16 + l15)*H_ + wv*256 + ks*32 + lho);

    f32x4 acc[4][4];
    #pragma unroll
    for (int ct = 0; ct < 4; ++ct)
      #pragma unroll
      for (int rt = 0; rt < 4; ++rt)
        acc[ct][rt] = (f32x4){0.f,0.f,0.f,0.f};

    // counted-vmcnt overlap: MFMA on slice ks while later slices load
    #pragma unroll
    for (int ks = 0; ks < 8; ++ks){
      asm volatile("s_waitcnt vmcnt(%0)" :: "i"(28 - 4*ks) : "memory");
      __builtin_amdgcn_sched_barrier(0);
      #pragma unroll
      for (int rt = 0; rt < 4; ++rt)
        #pragma unroll
        for (int ct = 0; ct < 4; ++ct)
          acc[ct][rt] = __builtin_amdgcn_mfma_f32_16x16x32_bf16(af[ks][rt], bfr[ct][ks], acc[ct][rt], 0,0,0);
    }

    // K-partials -> LDS
    #pragma unroll
    for (int ct = 0; ct < 4; ++ct)
      #pragma unroll
      for (int rt = 0; rt < 4; ++rt)
        *(f32x4*)&PSUM[wv][ct*16 + l15][rt*16 + (lane>>4)*4] = acc[ct][rt];
    __syncthreads();

    // reduce 4 K-quarters, compute gates and h update
    float hhr[4]={0,0,0,0}, hhz[4]={0,0,0,0}, hhn[4]={0,0,0,0};
    float mrz = 0.f, mn = 0.f;
    #pragma unroll
    for (int w = 0; w < 4; ++w){
      #pragma unroll
      for (int j = 0; j < 4; ++j){
        hhr[j] += PSUM[w][cq*4 + j][b];
        hhz[j] += PSUM[w][16 + cq*4 + j][b];
        hhn[j] += PSUM[w][32 + cq*4 + j][b];
      }
      mrz += PSUM[w][48][b];
      mn  += PSUM[w][49][b];
    }
    #pragma unroll
    for (int j = 0; j < 4; ++j){
      float R = sig_(bf16_to_f32(ir[j])  + gr[j]*(hhr[j]-mrz) + br_[j]);
      float Z = sig_(bf16_to_f32(izv[j]) + gz[j]*(hhz[j]-mrz) + bz_[j]);
      float N = tanh_(bf16_to_f32(inv[j]) + R*(gn[j]*(hhn[j]-mn) + bn_[j]));
      hv[j] = (1.0f - Z)*N + Z*hv[j];
    }
    *(f32x4*)(out + ((size_t)b*S_ + t)*H_ + c0) = (f32x4){hv[0],hv[1],hv[2],hv[3]};
    u16x4 h16;
    #pragma unroll
    for (int j = 0; j < 4; ++j) h16[j] = f32_to_bf16(hv[j]);
    stg8_coh(HB + (cur^1)*(B_*H_) + (size_t)b*H_ + c0, h16);

    // publish: all our stores at coherence point, then raise our flag
    asm volatile("s_waitcnt vmcnt(0)" ::: "memory");
    __syncthreads();
    if (tid == 0) stg4_coh((unsigned*)(FLAGS + g*16), (unsigned)(t+1));
    cur ^= 1;
  }
  #pragma unroll
  for (int j = 0; j < 4; ++j)
    out[(size_t)B_*S_*H_ + (size_t)b*H_ + c0 + j] = hv[j];
}

// ---------------- host launcher ---------------------------------------------
extern "C" void kernel_launch(void* const* d_in, const int* in_sizes, int n_in,
                              void* d_out, int out_size, void* d_ws, size_t ws_size,
                              hipStream_t stream){
  (void)in_sizes; (void)n_in; (void)out_size; (void)ws_size;
  const float* x   = (const float*)d_in[0];
  const float* st  = (const float*)d_in[1];
  const float* wih = (const float*)d_in[2];
  const float* whh = (const float*)d_in[3];
  const float* bih = (const float*)d_in[4];
  const float* bhh = (const float*)d_in[5];
  const float* gih = (const float*)d_in[6];
  const float* ghh = (const float*)d_in[7];
  float* out = (float*)d_out;
  char* ws = (char*)d_ws;

  unsigned short* IH    = (unsigned short*)(ws);                   // 201,326,592
  unsigned short* X16   = (unsigned short*)(ws + 201326592ull);    //  33,554,432
  unsigned short* WIH16 = (unsigned short*)(ws + 234881024ull);    //   3,145,728
  unsigned short* WHH16 = (unsigned short*)(ws + 238026752ull);    //   6,291,456
  unsigned short* CM16  = (unsigned short*)(ws + 244318208ull);    //      32,768
  unsigned short* HB    = (unsigned short*)(ws + 244350976ull);    //     262,144
  unsigned*       FLAGS = (unsigned*)      (ws + 244613120ull);    //       4,096

  hipMemsetAsync(FLAGS, 0, 4096, stream);
  k_cvt4<<<2048, 256, 0, stream>>>(x,   X16,   4194304);
  k_cvt4<<<1024, 256, 0, stream>>>(wih, WIH16, 393216);
  k_cvt4<<<1024, 256, 0, stream>>>(whh, WHH16, 786432);
  k_cvt4<<<64,   256, 0, stream>>>(st,  HB,    16384);
  k_cmean<<<4,   256, 0, stream>>>(whh, CM16);
  k_gemm_ih<<<6144, 256, 0, stream>>>(X16, WIH16, IH);
  k_ln<<<32768, 256, 0, stream>>>(IH, gih, bih);
  k_gru<<<NWG, 256, 0, stream>>>(IH, WHH16, CM16, HB, ghh, bhh, st, out, FLAGS);
}

// Round 4
// 3052.408 us; speedup vs baseline: 3.2655x; 1.3509x over previous
//
#include <hip/hip_runtime.h>
#include <stdint.h>
#include <stddef.h>

#define B_  64
#define S_  512
#define I_  512
#define H_  1024
#define G_  3072
#define NWG 64      // 32 col-strips x 2 batch-halves
#define CPW 32      // h-columns per wg

typedef short short8 __attribute__((ext_vector_type(8)));
typedef float f32x4  __attribute__((ext_vector_type(4)));
typedef unsigned short u16x4 __attribute__((ext_vector_type(4)));

__device__ __forceinline__ unsigned short f32_to_bf16(float f){
  unsigned u = __builtin_bit_cast(unsigned, f);
  u = (u + 0x7FFFu + ((u >> 16) & 1u)) >> 16;
  return (unsigned short)u;
}
__device__ __forceinline__ float bf16_to_f32(unsigned short s){
  unsigned u = ((unsigned)s) << 16;
  return __builtin_bit_cast(float, u);
}
__device__ __forceinline__ float sig_(float x){ return 1.0f/(1.0f + __expf(-x)); }
__device__ __forceinline__ float tanh_(float x){
  float ax = fabsf(x);
  float t = __expf(-2.0f*ax);
  float r = (1.0f - t)/(1.0f + t);
  return copysignf(r, x);
}

// coherent (cross-XCD visible) accesses: bypass L1/L2 via sc0 sc1
__device__ __forceinline__ short8 ldg16_coh(const unsigned short* p){
  short8 r;
  asm volatile("global_load_dwordx4 %0, %1, off sc0 sc1" : "=v"(r) : "v"(p) : "memory");
  return r;
}
__device__ __forceinline__ void stg8_coh(unsigned short* p, u16x4 v){
  asm volatile("global_store_dwordx2 %0, %1, off sc0 sc1" :: "v"(p), "v"(v) : "memory");
}
__device__ __forceinline__ void stg4_coh(unsigned* p, unsigned v){
  asm volatile("global_store_dword %0, %1, off sc0 sc1" :: "v"(p), "v"(v) : "memory");
}
__device__ __forceinline__ unsigned ldg4_coh_wait(const unsigned* p){
  unsigned r;
  asm volatile("global_load_dword %0, %1, off sc0 sc1\n\ts_waitcnt vmcnt(0)"
               : "=v"(r) : "v"(p) : "memory");
  return r;
}
__device__ __forceinline__ u16x4 ldg8(const unsigned short* p){
  u16x4 r;
  asm volatile("global_load_dwordx2 %0, %1, off" : "=v"(r) : "v"(p) : "memory");
  return r;
}

// ---------------- f32 -> bf16 cast ----------------
__global__ __launch_bounds__(256) void k_cvt4(const float* __restrict__ src,
                                              unsigned short* __restrict__ dst, int n4){
  int i = blockIdx.x*blockDim.x + threadIdx.x;
  int st = gridDim.x*blockDim.x;
  for (; i < n4; i += st){
    f32x4 v = *(const f32x4*)(src + (size_t)i*4);
    u16x4 o;
    o[0]=f32_to_bf16(v[0]); o[1]=f32_to_bf16(v[1]);
    o[2]=f32_to_bf16(v[2]); o[3]=f32_to_bf16(v[3]);
    *(u16x4*)(dst + (size_t)i*4) = o;
  }
}

// ---------------- column means of Whh -> CM[16][1024] -----------------------
__global__ __launch_bounds__(256) void k_cmean(const float* __restrict__ whh,
                                               unsigned short* __restrict__ CM){
  int k = blockIdx.x*256 + threadIdx.x;   // grid = 4 x 256 -> k in [0,1024)
  float s0 = 0.f, s1 = 0.f;
  for (int j = 0; j < 2048; ++j) s0 += whh[(size_t)j*H_ + k];
  for (int j = 2048; j < 3072; ++j) s1 += whh[(size_t)j*H_ + k];
  CM[k]      = f32_to_bf16(s0 * (1.0f/2048.0f));
  CM[H_ + k] = f32_to_bf16(s1 * (1.0f/1024.0f));
  for (int r = 2; r < 16; ++r) CM[(size_t)r*H_ + k] = 0;
}

// ---------------- ih = X @ Wih^T  (writes time-major: row' = s*64 + b) ------
__global__ __launch_bounds__(256, 2) void k_gemm_ih(
    const unsigned short* __restrict__ X,    // [32768][512]
    const unsigned short* __restrict__ W,    // [3072][512]
    unsigned short* __restrict__ IH)         // [512][64][3072]
{
  __shared__ __align__(16) short As[128*32];
  __shared__ __align__(16) short Bs[128*32];
  int bid = blockIdx.x;
  int mt = bid / 24, nt = bid % 24;
  int tid = threadIdx.x, lane = tid & 63, wid = tid >> 6;
  int vr = wid >> 1, vc = wid & 1;
  int r0s = tid >> 2, r1s = r0s + 64;
  int sc = (tid & 3) * 8;
  const unsigned short* xa0 = X + (size_t)(mt*128 + r0s)*512 + sc;
  const unsigned short* xa1 = X + (size_t)(mt*128 + r1s)*512 + sc;
  const unsigned short* wb0 = W + (size_t)(nt*128 + r0s)*512 + sc;
  const unsigned short* wb1 = W + (size_t)(nt*128 + r1s)*512 + sc;

  f32x4 acc[4][4];
  #pragma unroll
  for (int m=0;m<4;m++)
    #pragma unroll
    for (int n=0;n<4;n++) acc[m][n] = (f32x4){0.f,0.f,0.f,0.f};

  short8 ra0 = *(const short8*)xa0;
  short8 ra1 = *(const short8*)xa1;
  short8 rb0 = *(const short8*)wb0;
  short8 rb1 = *(const short8*)wb1;
  int ko = (lane >> 4) * 8;

  for (int kt = 0; kt < 16; ++kt){
    __syncthreads();
    *(short8*)&As[r0s*32 + sc] = ra0;
    *(short8*)&As[r1s*32 + sc] = ra1;
    *(short8*)&Bs[r0s*32 + sc] = rb0;
    *(short8*)&Bs[r1s*32 + sc] = rb1;
    __syncthreads();
    if (kt < 15){
      ra0 = *(const short8*)(xa0 + (kt+1)*32);
      ra1 = *(const short8*)(xa1 + (kt+1)*32);
      rb0 = *(const short8*)(wb0 + (kt+1)*32);
      rb1 = *(const short8*)(wb1 + (kt+1)*32);
    }
    short8 af[4], bfr[4];
    #pragma unroll
    for (int m=0;m<4;m++) af[m]  = *(const short8*)&As[(vr*64 + m*16 + (lane&15))*32 + ko];
    #pragma unroll
    for (int n=0;n<4;n++) bfr[n] = *(const short8*)&Bs[(vc*64 + n*16 + (lane&15))*32 + ko];
    #pragma unroll
    for (int m=0;m<4;m++)
      #pragma unroll
      for (int n=0;n<4;n++)
        acc[m][n] = __builtin_amdgcn_mfma_f32_16x16x32_bf16(af[m], bfr[n], acc[m][n], 0,0,0);
  }
  int row0 = mt*128 + vr*64, col0 = nt*128 + vc*64;
  int rl = (lane >> 4) * 4, cl = lane & 15;
  #pragma unroll
  for (int m=0;m<4;m++)
    #pragma unroll
    for (int n=0;n<4;n++)
      #pragma unroll
      for (int r=0;r<4;r++){
        int row = row0 + m*16 + rl + r;             // b*512 + s
        int rowT = ((row & 511) << 6) | (row >> 9); // s*64 + b
        IH[(size_t)rowT*G_ + (col0 + n*16 + cl)] = f32_to_bf16(acc[m][n][r]);
      }
}

// ---------------- row LayerNorm (ddof=1) over [0:2048) and [2048:3072) ------
__global__ __launch_bounds__(256) void k_ln(
    unsigned short* __restrict__ IH,
    const float* __restrict__ gih,
    const float* __restrict__ bih)
{
  __shared__ float red[4][4];
  int row = blockIdx.x, tid = threadIdx.x, lane = tid & 63, wid = tid >> 6;
  unsigned short* p = IH + (size_t)row * G_;
  float xv[3][4];
  #pragma unroll
  for (int q=0;q<3;q++){
    u16x4 v = *(const u16x4*)(p + (tid + q*256)*4);
    #pragma unroll
    for (int j=0;j<4;j++) xv[q][j] = bf16_to_f32(v[j]);
  }
  float s0=0, q0=0, s1=0, q1=0;
  #pragma unroll
  for (int q=0;q<2;q++)
    #pragma unroll
    for (int j=0;j<4;j++){ s0 += xv[q][j]; q0 += xv[q][j]*xv[q][j]; }
  #pragma unroll
  for (int j=0;j<4;j++){ s1 += xv[2][j]; q1 += xv[2][j]*xv[2][j]; }
  #pragma unroll
  for (int off=32; off>0; off>>=1){
    s0 += __shfl_down(s0, off, 64);
    q0 += __shfl_down(q0, off, 64);
    s1 += __shfl_down(s1, off, 64);
    q1 += __shfl_down(q1, off, 64);
  }
  if (lane == 0){ red[wid][0]=s0; red[wid][1]=q0; red[wid][2]=s1; red[wid][3]=q1; }
  __syncthreads();
  float S0 = red[0][0]+red[1][0]+red[2][0]+red[3][0];
  float Q0 = red[0][1]+red[1][1]+red[2][1]+red[3][1];
  float S1 = red[0][2]+red[1][2]+red[2][2]+red[3][2];
  float Q1 = red[0][3]+red[1][3]+red[2][3]+red[3][3];
  float m0 = S0 * (1.0f/2048.0f);
  float rs0 = rsqrtf(fmaxf((Q0 - S0*m0) * (1.0f/2047.0f), 1e-20f));
  float m1 = S1 * (1.0f/1024.0f);
  float rs1 = rsqrtf(fmaxf((Q1 - S1*m1) * (1.0f/1023.0f), 1e-20f));
  #pragma unroll
  for (int q=0;q<3;q++){
    int base = (tid + q*256)*4;
    u16x4 o;
    #pragma unroll
    for (int j=0;j<4;j++){
      int col = base + j;
      float y = (q<2) ? (xv[q][j]-m0)*rs0 : (xv[q][j]-m1)*rs1;
      o[j] = f32_to_bf16(gih[col]*y + bih[col]);
    }
    *(u16x4*)(p + base) = o;
  }
}

// ---------------- persistent GRU recurrence ---------------------------------
// 64 wgs = 32 col-strips x 2 independent batch-halves. Per wg: 32 cols, 32 rows.
__global__ __launch_bounds__(256, 1) void k_gru(
    const unsigned short* __restrict__ IH,   // [512][64][3072] bf16 post-LN
    const unsigned short* __restrict__ WHH,  // [3072][1024] bf16
    const unsigned short* __restrict__ CM,   // [16][1024] bf16
    unsigned short* __restrict__ HB,         // 2 x [64][1024] bf16 ping-pong
    const float* __restrict__ ghh,
    const float* __restrict__ bhh,
    const float* __restrict__ state,
    float* __restrict__ out,
    unsigned* __restrict__ FLAGS)            // 64 flags, 64B apart
{
  __shared__ float PSUM[4][112][34];
  const int g = blockIdx.x & 31;        // col-strip
  const int p = blockIdx.x >> 5;        // batch-half
  const int tid = threadIdx.x;
  const int lane = tid & 63;
  const int wv = tid >> 6;              // wave = K-quarter owner
  const int l15 = lane & 15;
  const int lho = (lane >> 4) << 3;
  const int colbase = g * CPW;
  const int rowbase = p * 32;

  // persistent B fragments: 6 gate col-tiles + 1 mean tile (K-quarter per wave)
  short8 bfr[7][8];
  #pragma unroll
  for (int ct = 0; ct < 7; ++ct){
    const unsigned short* src = (ct < 6)
        ? (WHH + (size_t)((ct>>1)*H_ + colbase + (ct&1)*16 + l15)*H_)
        : (CM + (size_t)l15*H_);
    #pragma unroll
    for (int ks = 0; ks < 8; ++ks)
      bfr[ct][ks] = *(const short8*)(src + wv*256 + ks*32 + lho);
  }

  // gate-phase ownership: thread = (batch row b_, col-quad cq)
  const int b_ = tid & 31;              // 32 rows in this half
  const int cq = tid >> 5;              // 8 col-quads of 4
  const int c0 = colbase + cq*4;
  const int gb = rowbase + b_;          // global batch
  float gr[4],gz[4],gn[4],br_[4],bz_[4],bn_[4],hv[4];
  #pragma unroll
  for (int j = 0; j < 4; ++j){
    gr[j] = ghh[c0+j];   gz[j] = ghh[H_+c0+j];   gn[j] = ghh[2*H_+c0+j];
    br_[j]= bhh[c0+j];   bz_[j]= bhh[H_+c0+j];   bn_[j]= bhh[2*H_+c0+j];
    hv[j] = state[(size_t)gb*H_ + c0 + j];
  }

  // poll flags of my half only (2 lanes per flag)
  const unsigned* myflag = FLAGS + (p*32 + (lane & 31))*16;
  int cur = 0;

  for (int t = 0; t < S_; ++t){
    // ih gate inputs — issue before the poll so they ride under the wait
    const unsigned short* ihp = IH + ((size_t)t*B_ + gb)*G_;
    u16x4 ir  = ldg8(ihp + c0);
    u16x4 izv = ldg8(ihp + H_ + c0);
    u16x4 inv = ldg8(ihp + 2*H_ + c0);

    // flag-array barrier over my half's 32 producers
    for (;;){
      unsigned v = ldg4_coh_wait(myflag);
      if (__all((int)(v >= (unsigned)t))) break;
    }

    // A fragments: coherent read of my half's 32-row h panel, ks-major
    const unsigned short* hb = HB + cur*(B_*H_);
    short8 af[8][2];
    #pragma unroll
    for (int ks = 0; ks < 8; ++ks)
      #pragma unroll
      for (int rt = 0; rt < 2; ++rt)
        af[ks][rt] = ldg16_coh(hb + (size_t)(rowbase + rt*16 + l15)*H_ + wv*256 + ks*32 + lho);

    f32x4 acc[7][2];
    #pragma unroll
    for (int ct = 0; ct < 7; ++ct)
      #pragma unroll
      for (int rt = 0; rt < 2; ++rt)
        acc[ct][rt] = (f32x4){0.f,0.f,0.f,0.f};

    // counted-vmcnt overlap: MFMA on slice ks while later slices load
    #pragma unroll
    for (int ks = 0; ks < 8; ++ks){
      asm volatile("s_waitcnt vmcnt(%0)" :: "i"(14 - 2*ks) : "memory");
      __builtin_amdgcn_sched_barrier(0);
      #pragma unroll
      for (int rt = 0; rt < 2; ++rt)
        #pragma unroll
        for (int ct = 0; ct < 7; ++ct)
          acc[ct][rt] = __builtin_amdgcn_mfma_f32_16x16x32_bf16(af[ks][rt], bfr[ct][ks], acc[ct][rt], 0,0,0);
    }

    // K-partials -> LDS
    #pragma unroll
    for (int ct = 0; ct < 7; ++ct)
      #pragma unroll
      for (int rt = 0; rt < 2; ++rt)
        *(f32x4*)&PSUM[wv][ct*16 + l15][rt*16 + (lane>>4)*4] = acc[ct][rt];
    __syncthreads();

    // reduce 4 K-quarters; gates and h update
    float hhr[4]={0,0,0,0}, hhz[4]={0,0,0,0}, hhn[4]={0,0,0,0};
    float mrz = 0.f, mn = 0.f;
    #pragma unroll
    for (int w = 0; w < 4; ++w){
      #pragma unroll
      for (int j = 0; j < 4; ++j){
        hhr[j] += PSUM[w][cq*4 + j][b_];
        hhz[j] += PSUM[w][32 + cq*4 + j][b_];
        hhn[j] += PSUM[w][64 + cq*4 + j][b_];
      }
      mrz += PSUM[w][96][b_];
      mn  += PSUM[w][97][b_];
    }
    f32x4 ho;
    #pragma unroll
    for (int j = 0; j < 4; ++j){
      float R = sig_(bf16_to_f32(ir[j])  + gr[j]*(hhr[j]-mrz) + br_[j]);
      float Z = sig_(bf16_to_f32(izv[j]) + gz[j]*(hhz[j]-mrz) + bz_[j]);
      float N = tanh_(bf16_to_f32(inv[j]) + R*(gn[j]*(hhn[j]-mn) + bn_[j]));
      hv[j] = (1.0f - Z)*N + Z*hv[j];
      ho[j] = hv[j];
    }
    u16x4 h16;
    #pragma unroll
    for (int j = 0; j < 4; ++j) h16[j] = f32_to_bf16(hv[j]);
    stg8_coh(HB + (cur^1)*(B_*H_) + (size_t)gb*H_ + c0, h16);

    // publish: h16 at coherence point -> raise flag; out store rides after
    asm volatile("s_waitcnt vmcnt(0)" ::: "memory");
    __syncthreads();
    if (tid == 0) stg4_coh((unsigned*)(FLAGS + (p*32 + g)*16), (unsigned)(t+1));
    *(f32x4*)(out + ((size_t)gb*S_ + t)*H_ + c0) = ho;
    cur ^= 1;
  }
  #pragma unroll
  for (int j = 0; j < 4; ++j)
    out[(size_t)B_*S_*H_ + (size_t)gb*H_ + c0 + j] = hv[j];
}

// ---------------- host launcher ---------------------------------------------
extern "C" void kernel_launch(void* const* d_in, const int* in_sizes, int n_in,
                              void* d_out, int out_size, void* d_ws, size_t ws_size,
                              hipStream_t stream){
  (void)in_sizes; (void)n_in; (void)out_size; (void)ws_size;
  const float* x   = (const float*)d_in[0];
  const float* st  = (const float*)d_in[1];
  const float* wih = (const float*)d_in[2];
  const float* whh = (const float*)d_in[3];
  const float* bih = (const float*)d_in[4];
  const float* bhh = (const float*)d_in[5];
  const float* gih = (const float*)d_in[6];
  const float* ghh = (const float*)d_in[7];
  float* out = (float*)d_out;
  char* ws = (char*)d_ws;

  unsigned short* IH    = (unsigned short*)(ws);                   // 201,326,592
  unsigned short* X16   = (unsigned short*)(ws + 201326592ull);    //  33,554,432
  unsigned short* WIH16 = (unsigned short*)(ws + 234881024ull);    //   3,145,728
  unsigned short* WHH16 = (unsigned short*)(ws + 238026752ull);    //   6,291,456
  unsigned short* CM16  = (unsigned short*)(ws + 244318208ull);    //      32,768
  unsigned short* HB    = (unsigned short*)(ws + 244350976ull);    //     262,144
  unsigned*       FLAGS = (unsigned*)      (ws + 244613120ull);    //       4,096

  hipMemsetAsync(FLAGS, 0, 4096, stream);
  k_cvt4<<<2048, 256, 0, stream>>>(x,   X16,   4194304);
  k_cvt4<<<1024, 256, 0, stream>>>(wih, WIH16, 393216);
  k_cvt4<<<1024, 256, 0, stream>>>(whh, WHH16, 786432);
  k_cvt4<<<64,   256, 0, stream>>>(st,  HB,    16384);
  k_cmean<<<4,   256, 0, stream>>>(whh, CM16);
  k_gemm_ih<<<6144, 256, 0, stream>>>(X16, WIH16, IH);
  k_ln<<<32768, 256, 0, stream>>>(IH, gih, bih);
  k_gru<<<NWG, 256, 0, stream>>>(IH, WHH16, CM16, HB, ghh, bhh, st, out, FLAGS);
}